// Round 4
// baseline (395.970 us; speedup 1.0000x reference)
//
#include <hip/hip_runtime.h>
#include <hip/hip_bf16.h>
#include <stdint.h>

typedef unsigned short u16;
typedef __attribute__((ext_vector_type(8))) short short8;
typedef __attribute__((ext_vector_type(4))) float f32x4;
typedef __attribute__((ext_vector_type(4))) unsigned short u16x4;

constexpr int BB = 2, SS = 2048, HSZ = 2048, NH = 16, NKV = 4, DH = 128;
constexpr int MROWS = BB * SS;             // 4096
constexpr int NQKV = (NH + 2 * NKV) * DH;  // 3072
constexpr float RMS_EPS = 1e-6f;

__device__ __forceinline__ u16 f2bf(float f) {
  __hip_bfloat16 h = __float2bfloat16(f);
  return *reinterpret_cast<u16*>(&h);
}
__device__ __forceinline__ float bf2f(u16 u) {
  __hip_bfloat16 h;
  *reinterpret_cast<u16*>(&h) = u;
  return __bfloat162float(h);
}

__device__ __forceinline__ void gld16(const void* g, void* l) {
  __builtin_amdgcn_global_load_lds(
      (const __attribute__((address_space(1))) void*)g,
      (__attribute__((address_space(3))) void*)l, 16, 0, 0);
}

// ---------------- fp32 -> bf16 conversion (vectorized) ----------------
__global__ void cvt_bf16_kernel(const float* __restrict__ in, u16* __restrict__ out, int n4) {
  int i = blockIdx.x * blockDim.x + threadIdx.x;
  if (i >= n4) return;
  float4 v = reinterpret_cast<const float4*>(in)[i];
  u16x4 o;
  o.x = f2bf(v.x); o.y = f2bf(v.y); o.z = f2bf(v.z); o.w = f2bf(v.w);
  reinterpret_cast<u16x4*>(out)[i] = o;
}

// ---------------- GEMM 256x256: C[M][N] = A[M][K] @ B[N][K]^T ----------------
// 512 threads (8 waves, 2M x 4N; wave tile 128x64). BK=32. 4-deep LDS ring:
// stage tile t+2 at iter top via global_load_lds(16B), counted vmcnt(8/4/0)
// (never drain mid-loop - T4), raw s_barrier x2/iter, setprio on MFMA (T5).
// BK=32 rows are 64B (16 banks) -> ds_read_b128 frags are 2-way = free (m136),
// so linear LDS + global_load_lds is conflict-clean without swizzle.
template <typename OutT>
__global__ __launch_bounds__(512, 2) void gemm256(
    const u16* __restrict__ A, const u16* __restrict__ Bm, OutT* __restrict__ C,
    int M, int N, int K, int nbn) {
  __shared__ u16 Abuf[4][256 * 32];
  __shared__ u16 Bbuf[4][256 * 32];
  const int tid = threadIdx.x;
  const int wave = tid >> 6;
  const int lane = tid & 63;
  // XCD-aware swizzle (grid % 8 == 0 for both uses)
  const int nwg = gridDim.x;
  const int bid = blockIdx.x;
  const int wg = (bid & 7) * (nwg >> 3) + (bid >> 3);
  const int bm = wg / nbn, bn = wg % nbn;
  const int row0 = bm * 256, col0 = bn * 256;
  const int wm = wave >> 2, wn = wave & 3;
  const int lr = lane & 15, g = lane >> 4;
  // staging geometry: load j covers rows j*128 + wave*16 + (lane>>2), chunk lane&3
  const int sra = wave * 16 + (lane >> 2);
  const int sca = (lane & 3) * 8;
  const int lda0 = (wave * 16) * 32;          // wave-uniform LDS elem offset
  const int lda1 = (128 + wave * 16) * 32;

  f32x4 acc[8][4] = {};
  const int nt = K / 32;

#define STAGE(T, BUFI)                                                        \
  {                                                                           \
    const int k0_ = (T) * 32;                                                 \
    u16* Ab_ = &Abuf[(BUFI)][0];                                              \
    u16* Bb_ = &Bbuf[(BUFI)][0];                                              \
    gld16(A + (size_t)(row0 + sra) * K + k0_ + sca, Ab_ + lda0);              \
    gld16(A + (size_t)(row0 + 128 + sra) * K + k0_ + sca, Ab_ + lda1);        \
    gld16(Bm + (size_t)(col0 + sra) * K + k0_ + sca, Bb_ + lda0);             \
    gld16(Bm + (size_t)(col0 + 128 + sra) * K + k0_ + sca, Bb_ + lda1);       \
  }

  STAGE(0, 0);
  STAGE(1, 1);

  for (int t = 0; t < nt; t++) {
    if (t + 2 < nt) {
      STAGE(t + 2, (t + 2) & 3);
      asm volatile("s_waitcnt vmcnt(8)" ::: "memory");  // tile t landed; t+1,t+2 fly
    } else if (t + 1 < nt) {
      asm volatile("s_waitcnt vmcnt(4)" ::: "memory");
    } else {
      asm volatile("s_waitcnt vmcnt(0)" ::: "memory");
    }
    __builtin_amdgcn_s_barrier();          // all waves' tile-t loads landed
    __builtin_amdgcn_sched_barrier(0);     // no motion across the barrier

    const u16* Ab = &Abuf[t & 3][0];
    const u16* Bb = &Bbuf[t & 3][0];
    short8 af[8], bfr[4];
#pragma unroll
    for (int m = 0; m < 8; m++)
      af[m] = *(const short8*)&Ab[(wm * 128 + m * 16 + lr) * 32 + g * 8];
#pragma unroll
    for (int n = 0; n < 4; n++)
      bfr[n] = *(const short8*)&Bb[(wn * 64 + n * 16 + lr) * 32 + g * 8];

    __builtin_amdgcn_s_setprio(1);
#pragma unroll
    for (int m = 0; m < 8; m++)
#pragma unroll
      for (int n = 0; n < 4; n++)
        acc[m][n] = __builtin_amdgcn_mfma_f32_16x16x32_bf16(af[m], bfr[n], acc[m][n], 0, 0, 0);
    __builtin_amdgcn_s_setprio(0);

    __builtin_amdgcn_s_barrier();          // all waves done reading buf[t&3]
    __builtin_amdgcn_sched_barrier(0);
  }
#undef STAGE

  const int cr = g * 4, cc = lr;
#pragma unroll
  for (int m = 0; m < 8; m++) {
#pragma unroll
    for (int n = 0; n < 4; n++) {
#pragma unroll
      for (int r = 0; r < 4; r++) {
        size_t idx = (size_t)(row0 + wm * 128 + m * 16 + cr + r) * N +
                     (col0 + wn * 64 + n * 16 + cc);
        if constexpr (sizeof(OutT) == 2) C[idx] = (OutT)f2bf(acc[m][n][r]);
        else C[idx] = acc[m][n][r];
      }
    }
  }
}

// ---------------- RMS-norm (q,k heads) + RoPE + split/cast --------------------
// One block per (b,s) row of C_qkv[4096][3072]; wave handles heads wave,wave+4,...
// Q heads get D^-0.5 * log2(e) folded in (attn uses exp2 with static max).
__global__ __launch_bounds__(256) void postproc_kernel(
    const u16* __restrict__ Cqkv, const float* __restrict__ cosT,
    const float* __restrict__ sinT, const float* __restrict__ qw,
    const float* __restrict__ kw, u16* __restrict__ qO, u16* __restrict__ kO,
    u16* __restrict__ vO) {
  const int row = blockIdx.x;
  const int b = row / SS, s = row % SS;
  const int wave = threadIdx.x >> 6, lane = threadIdx.x & 63;
  const u16* base = Cqkv + (size_t)row * NQKV;
  const int d0 = lane * 2;
  const float ATT_SCALE = 0.08838834764831843f * 1.4426950408889634f;  // D^-0.5 * log2e
  for (int hd = wave; hd < NH + 2 * NKV; hd += 4) {
    const u16* hp = base + hd * DH;
    ushort2 raw = *(const ushort2*)(hp + d0);
    if (hd < NH + NKV) {
      float v0 = bf2f(raw.x), v1 = bf2f(raw.y);
      float ss = v0 * v0 + v1 * v1;
#pragma unroll
      for (int off = 32; off > 0; off >>= 1) ss += __shfl_xor(ss, off);
      float inv = rsqrtf(ss * (1.0f / DH) + RMS_EPS);
      const float* w = (hd < NH) ? qw : kw;
      float n0 = v0 * inv * w[d0], n1 = v1 * inv * w[d0 + 1];
      // rotate_half: lane<32 holds d<64, partner lane^32 holds d^64
      float r0 = __shfl_xor(n0, 32), r1 = __shfl_xor(n1, 32);
      float sgn = (lane < 32) ? -1.f : 1.f;
      float c0 = cosT[s * DH + d0], c1 = cosT[s * DH + d0 + 1];
      float s0 = sinT[s * DH + d0], s1 = sinT[s * DH + d0 + 1];
      float o0 = n0 * c0 + sgn * r0 * s0;
      float o1 = n1 * c1 + sgn * r1 * s1;
      ushort2 o;
      if (hd < NH) {
        o.x = f2bf(o0 * ATT_SCALE);
        o.y = f2bf(o1 * ATT_SCALE);
        *(ushort2*)(qO + ((size_t)((b * NH + hd) * SS + s)) * DH + d0) = o;
      } else {
        o.x = f2bf(o0);
        o.y = f2bf(o1);
        *(ushort2*)(kO + ((size_t)((b * NKV + hd - NH) * SS + s)) * DH + d0) = o;
      }
    } else {
      *(ushort2*)(vO + ((size_t)((b * NKV + hd - NH - NKV) * SS + s)) * DH + d0) = raw;
    }
  }
}

// ---------------- V transpose: [b,hkv][S][D] -> [b,hkv][D][S] ----------------
__global__ __launch_bounds__(256) void transpose_v_kernel(const u16* __restrict__ v,
                                                          u16* __restrict__ vt) {
  __shared__ u16 tile[64][68];  // pad to 68 for bank spread + 8B alignment
  const int bh = blockIdx.z;
  const int st = blockIdx.x * 64;
  const int dt = blockIdx.y * 64;
  const int tid = threadIdx.x;
  const u16* src = v + ((size_t)bh * SS + st) * DH + dt;
#pragma unroll
  for (int it = 0; it < 4; it++) {
    int r = (tid >> 4) + it * 16, c = (tid & 15) * 4;
    *(u16x4*)&tile[r][c] = *(const u16x4*)(src + (size_t)r * DH + c);
  }
  __syncthreads();
  u16* dst = vt + ((size_t)bh * DH + dt) * SS + st;
#pragma unroll
  for (int it = 0; it < 4; it++) {
    int r2 = (tid >> 4) + it * 16, c2 = (tid & 15) * 4;
    u16x4 o;
    o.x = tile[c2][r2]; o.y = tile[c2 + 1][r2];
    o.z = tile[c2 + 2][r2]; o.w = tile[c2 + 3][r2];
    *(u16x4*)(dst + (size_t)r2 * SS + c2) = o;
  }
}

// ---------------- causal GQA flash attention ---------------------------------
// grid (S/128 pairs, H, B); 4 waves; wave owns 16 q-rows; KV tiles of 64.
// Block processes q-tiles {pid, 31-pid} sequentially -> uniform 33 tile-units.
// Swapped QK^T (mfma(K,Q)): lane holds S^T[kv=(l>>4)*4+r+16n][q=l&15] ->
// softmax row-sum = in-lane + 2 shfl. Static max (|S|<=sqrt(D)=11.31, exact:
// RMS-normed q,k + RoPE rotation): p = exp2(S' - 12*log2e), no rescale.
__global__ __launch_bounds__(256, 2) void attn_kernel(
    const u16* __restrict__ Q, const u16* __restrict__ Kb,
    const u16* __restrict__ Vt, u16* __restrict__ O) {
  __shared__ __align__(16) u16 Ks[64 * 128];
  __shared__ __align__(16) u16 Vs[128 * 64];
  __shared__ __align__(16) u16 Plds[4][16 * 64];  // per-wave P buffer (2KB)
  const int pid = blockIdx.x, h = blockIdx.y, b = blockIdx.z;
  const int hkv = h >> 2;
  const int tid = threadIdx.x;
  const int wave = tid >> 6, lane = tid & 63;
  const int lr = lane & 15, g = lane >> 4;
  const u16* qbase = Q + ((size_t)(b * NH + h) * SS) * DH;
  const u16* kbase = Kb + ((size_t)(b * NKV + hkv) * SS) * DH;
  const u16* vbase = Vt + ((size_t)(b * NKV + hkv) * DH) * SS;

  // staging geometry (reg-staged so LDS writes can be XOR-swizzled)
  const int krow = tid >> 4;                       // 0..15 (+16*i)
  const int kcol = (tid & 15) * 8;                 // element col in 128-wide row
  const int kswz = kcol ^ ((krow & 7) << 3);       // 16B-block XOR swizzle
  const int vrow = tid >> 3;                       // 0..31 (+32*i)
  const int vcol = (tid & 7) * 8;                  // element col in 64-wide row
  const int vswz = vcol ^ ((vrow & 7) << 3);
  const int kx = (lr & 7) << 3;                    // read-side XOR (elements)
  const int psw = (lr & 7) << 4;                   // Plds byte XOR (row period 128B)
  char* pl = (char*)&Plds[wave][0];

  int4 kr0, kr1, kr2, kr3, vr0, vr1, vr2, vr3;
#define STAGE_LOAD(T)                                                         \
  {                                                                           \
    const int kv0_ = (T) * 64;                                                \
    kr0 = *(const int4*)(kbase + (size_t)(kv0_ + krow) * DH + kcol);          \
    kr1 = *(const int4*)(kbase + (size_t)(kv0_ + krow + 16) * DH + kcol);     \
    kr2 = *(const int4*)(kbase + (size_t)(kv0_ + krow + 32) * DH + kcol);     \
    kr3 = *(const int4*)(kbase + (size_t)(kv0_ + krow + 48) * DH + kcol);     \
    vr0 = *(const int4*)(vbase + (size_t)(vrow) * SS + kv0_ + vcol);          \
    vr1 = *(const int4*)(vbase + (size_t)(vrow + 32) * SS + kv0_ + vcol);     \
    vr2 = *(const int4*)(vbase + (size_t)(vrow + 64) * SS + kv0_ + vcol);     \
    vr3 = *(const int4*)(vbase + (size_t)(vrow + 96) * SS + kv0_ + vcol);     \
  }
#define STAGE_WRITE()                                                         \
  {                                                                           \
    *(int4*)&Ks[(krow) * DH + kswz] = kr0;                                    \
    *(int4*)&Ks[(krow + 16) * DH + kswz] = kr1;                               \
    *(int4*)&Ks[(krow + 32) * DH + kswz] = kr2;                               \
    *(int4*)&Ks[(krow + 48) * DH + kswz] = kr3;                               \
    *(int4*)&Vs[(vrow) * 64 + vswz] = vr0;                                    \
    *(int4*)&Vs[(vrow + 32) * 64 + vswz] = vr1;                               \
    *(int4*)&Vs[(vrow + 64) * 64 + vswz] = vr2;                               \
    *(int4*)&Vs[(vrow + 96) * 64 + vswz] = vr3;                               \
  }

#pragma unroll 1
  for (int half = 0; half < 2; half++) {
    const int qt = half ? (SS / 64 - 1 - pid) : pid;
    const int q0 = qt * 64 + wave * 16;
    const int nt = qt + 1;  // uniform across block

    short8 qf[4];
#pragma unroll
    for (int c = 0; c < 4; c++)
      qf[c] = *(const short8*)(qbase + (size_t)(q0 + lr) * DH + c * 32 + g * 8);

    f32x4 o_acc[8] = {};
    float l_run = 0.f;

    STAGE_LOAD(0);
    STAGE_WRITE();
    __syncthreads();

    for (int t = 0; t < nt; t++) {
      const int kv0 = t * 64;
      if (t + 1 < nt) STAGE_LOAD(t + 1);  // in-flight under compute (T14)

      // ---- swapped QK^T: S^T[64 kv][16 q] (A=K, B=Q; fragments identical) ----
      f32x4 sf[4] = {};
      __builtin_amdgcn_s_setprio(1);
#pragma unroll
      for (int n = 0; n < 4; n++) {
#pragma unroll
        for (int c = 0; c < 4; c++) {
          short8 kf = *(const short8*)&Ks[(n * 16 + lr) * DH + ((c * 32 + g * 8) ^ kx)];
          sf[n] = __builtin_amdgcn_mfma_f32_16x16x32_bf16(kf, qf[c], sf[n], 0, 0, 0);
        }
      }
      __builtin_amdgcn_s_setprio(0);

      // ---- softmax, static max: lane holds S[kv=16n+4g+r][q=q0+lr] ----
      const int qabs = q0 + lr;
      float p[4][4];
      float rs = 0.f;
#pragma unroll
      for (int n = 0; n < 4; n++) {
#pragma unroll
        for (int r = 0; r < 4; r++) {
          const int kvabs = kv0 + n * 16 + g * 4 + r;
          float e = exp2f(sf[n][r] - 17.312340490667562f);  // 12*log2e
          e = (kvabs <= qabs) ? e : 0.f;
          p[n][r] = e;
          rs += e;
        }
      }
      rs += __shfl_xor(rs, 16);
      rs += __shfl_xor(rs, 32);
      l_run += rs;

      // ---- pack P -> bf16, wave-private LDS (vectorized, swizzled) ----
#pragma unroll
      for (int n = 0; n < 4; n++) {
        uint2 wv;
        wv.x = (unsigned)f2bf(p[n][0]) | ((unsigned)f2bf(p[n][1]) << 16);
        wv.y = (unsigned)f2bf(p[n][2]) | ((unsigned)f2bf(p[n][3]) << 16);
        *(uint2*)(pl + lr * 128 + ((32 * n + 8 * g) ^ psw)) = wv;
      }

      // ---- PV: O[16 q][128 d] += P[16][64] @ V[64][128] ----
      __builtin_amdgcn_s_setprio(1);
#pragma unroll
      for (int c2 = 0; c2 < 2; c2++) {
        short8 pf = *(const short8*)(pl + lr * 128 + ((64 * c2 + 16 * g) ^ psw));
#pragma unroll
        for (int n2 = 0; n2 < 8; n2++) {
          short8 vf = *(const short8*)&Vs[(n2 * 16 + lr) * 64 + ((c2 * 32 + g * 8) ^ kx)];
          o_acc[n2] = __builtin_amdgcn_mfma_f32_16x16x32_bf16(pf, vf, o_acc[n2], 0, 0, 0);
        }
      }
      __builtin_amdgcn_s_setprio(0);

      __syncthreads();                      // all waves done reading Ks/Vs
      if (t + 1 < nt) STAGE_WRITE();        // compiler inserts vmcnt wait here
      __syncthreads();                      // staged tile visible
    }

    // ---- epilogue: O row = g*4+r (PV C-layout); l lives in lane (.&15)==row ----
#pragma unroll
    for (int r = 0; r < 4; r++) {
      const float ls = __shfl(l_run, (g << 4) | (g * 4 + r));
      const float inv = 1.0f / ls;
      u16* orow = O + ((size_t)(b * SS + q0 + g * 4 + r)) * (NH * DH) + h * DH;
#pragma unroll
      for (int n2 = 0; n2 < 8; n2++) orow[n2 * 16 + lr] = f2bf(o_acc[n2][r] * inv);
    }
  }
#undef STAGE_LOAD
#undef STAGE_WRITE
}

// -----------------------------------------------------------------------------
extern "C" void kernel_launch(void* const* d_in, const int* in_sizes, int n_in,
                              void* d_out, int out_size, void* d_ws, size_t ws_size,
                              hipStream_t stream) {
  const float* x    = (const float*)d_in[0];
  const float* cosT = (const float*)d_in[1];
  const float* sinT = (const float*)d_in[2];
  // d_in[3] = mask (causal, reconstructed analytically)
  const float* wq = (const float*)d_in[4];
  const float* wk = (const float*)d_in[5];
  const float* wv = (const float*)d_in[6];
  const float* wo = (const float*)d_in[7];
  const float* qw = (const float*)d_in[8];
  const float* kw = (const float*)d_in[9];
  float* out = (float*)d_out;

  char* p = (char*)d_ws;
  u16* xb    = (u16*)p; p += (size_t)MROWS * HSZ * 2;
  u16* wqkvb = (u16*)p; p += (size_t)NQKV * HSZ * 2;
  u16* wob   = (u16*)p; p += (size_t)HSZ * HSZ * 2;
  u16* cqkv  = (u16*)p; p += (size_t)MROWS * NQKV * 2;
  u16* qb    = (u16*)p; p += (size_t)BB * NH * SS * DH * 2;
  u16* kb    = (u16*)p; p += (size_t)BB * NKV * SS * DH * 2;
  u16* vb    = (u16*)p; p += (size_t)BB * NKV * SS * DH * 2;
  u16* vtb   = (u16*)p; p += (size_t)BB * NKV * SS * DH * 2;
  u16* aob   = (u16*)p; p += (size_t)MROWS * HSZ * 2;

  auto cvt = [&](const float* in, u16* o, size_t n) {
    int n4 = (int)(n / 4);
    cvt_bf16_kernel<<<dim3((n4 + 255) / 256), dim3(256), 0, stream>>>(in, o, n4);
  };
  cvt(x, xb, (size_t)MROWS * HSZ);
  cvt(wq, wqkvb, (size_t)NH * DH * HSZ);
  cvt(wk, wqkvb + (size_t)NH * DH * HSZ, (size_t)NKV * DH * HSZ);
  cvt(wv, wqkvb + (size_t)(NH + NKV) * DH * HSZ, (size_t)NKV * DH * HSZ);
  cvt(wo, wob, (size_t)HSZ * HSZ);

  gemm256<u16><<<dim3((MROWS / 256) * (NQKV / 256)), dim3(512), 0, stream>>>(
      xb, wqkvb, cqkv, MROWS, NQKV, HSZ, NQKV / 256);
  postproc_kernel<<<dim3(MROWS), dim3(256), 0, stream>>>(cqkv, cosT, sinT, qw, kw, qb, kb, vb);
  transpose_v_kernel<<<dim3(SS / 64, DH / 64, BB * NKV), dim3(256), 0, stream>>>(vb, vtb);
  attn_kernel<<<dim3(SS / 128, NH, BB), dim3(256), 0, stream>>>(qb, kb, vtb, aob);
  gemm256<float><<<dim3((MROWS / 256) * (HSZ / 256)), dim3(512), 0, stream>>>(
      aob, wob, out, MROWS, HSZ, HSZ, HSZ / 256);
}

// Round 5
// 366.128 us; speedup vs baseline: 1.0815x; 1.0815x over previous
//
#include <hip/hip_runtime.h>
#include <hip/hip_bf16.h>
#include <stdint.h>

typedef unsigned short u16;
typedef __attribute__((ext_vector_type(8))) short short8;
typedef __attribute__((ext_vector_type(4))) float f32x4;
typedef __attribute__((ext_vector_type(4))) unsigned short u16x4;

constexpr int BB = 2, SS = 2048, HSZ = 2048, NH = 16, NKV = 4, DH = 128;
constexpr int MROWS = BB * SS;             // 4096
constexpr int NQKV = (NH + 2 * NKV) * DH;  // 3072
constexpr float RMS_EPS = 1e-6f;

__device__ __forceinline__ u16 f2bf(float f) {
  __hip_bfloat16 h = __float2bfloat16(f);
  return *reinterpret_cast<u16*>(&h);
}
__device__ __forceinline__ float bf2f(u16 u) {
  __hip_bfloat16 h;
  *reinterpret_cast<u16*>(&h) = u;
  return __bfloat162float(h);
}

__device__ __forceinline__ void gld16(const void* g, void* l) {
  __builtin_amdgcn_global_load_lds(
      (const __attribute__((address_space(1))) void*)g,
      (__attribute__((address_space(3))) void*)l, 16, 0, 0);
}

// ---------------- fp32 -> bf16 conversion: all 5 tensors, one launch ---------
constexpr int N_X = MROWS * HSZ;      // 8388608
constexpr int N_WQ = NH * DH * HSZ;   // 4194304
constexpr int N_WK = NKV * DH * HSZ;  // 1048576
constexpr int N_WO = HSZ * HSZ;       // 4194304
__global__ void cvt_all_kernel(const float* __restrict__ x, const float* __restrict__ wq,
                               const float* __restrict__ wk, const float* __restrict__ wv,
                               const float* __restrict__ wo, u16* __restrict__ xb,
                               u16* __restrict__ wqkvb, u16* __restrict__ wob) {
  const int X4 = N_X / 4, Q4 = N_WQ / 4, K4 = N_WK / 4;
  int i = blockIdx.x * blockDim.x + threadIdx.x;
  const float* src;
  u16* dst;
  int off;
  if (i < X4) { src = x; dst = xb; off = i; }
  else if (i < X4 + Q4) { src = wq; dst = wqkvb; off = i - X4; }
  else if (i < X4 + Q4 + K4) { src = wk; dst = wqkvb + N_WQ; off = i - X4 - Q4; }
  else if (i < X4 + Q4 + 2 * K4) { src = wv; dst = wqkvb + N_WQ + N_WK; off = i - X4 - Q4 - K4; }
  else { src = wo; dst = wob; off = i - X4 - Q4 - 2 * K4; }
  float4 v = reinterpret_cast<const float4*>(src)[off];
  u16x4 o;
  o.x = f2bf(v.x); o.y = f2bf(v.y); o.z = f2bf(v.z); o.w = f2bf(v.w);
  reinterpret_cast<u16x4*>(dst)[off] = o;
}

// ---------------- GEMM 256x256: C[M][N] = A[M][K] @ B[N][K]^T ----------------
// 512 threads (8 waves, 2M x 4N; wave tile 128x64). BK=32, ring-4 K-tile slots.
// Iteration: compute K-tiles 2i,2i+1 (slots (2i)&3,(2i+1)&3), stage 2i+2,2i+3
// into slots ^2 (disjoint -> race-free). 4 phases/iter, 16 MFMA each, counted
// vmcnt(4) at phases 1/3 only (T4), setprio on MFMA (T5).
// LDS layout (T2): chunk g of row r at (r&~7)*64 + g*128 + ((r&7)^g)*16 ->
// wave b128 read = 64 distinct 16B slots = conflict-free. global_load_lds
// writes linearly; permutation applied to the global SOURCE address (rule 21).
template <typename OutT>
__global__ __launch_bounds__(512, 2) void gemm256(
    const u16* __restrict__ A, const u16* __restrict__ Bm, OutT* __restrict__ C,
    int M, int N, int K, int nbn) {
  __shared__ __align__(16) u16 AS[4][256 * 32];
  __shared__ __align__(16) u16 BS[4][256 * 32];
  const int tid = threadIdx.x;
  const int wave = tid >> 6, lane = tid & 63;
  const int nwg = gridDim.x, bid = blockIdx.x;
  const int wg = (bid & 7) * (nwg >> 3) + (bid >> 3);  // XCD swizzle (nwg%8==0)
  const int bm = wg / nbn, bn = wg % nbn;
  const int row0 = bm * 256, col0 = bn * 256;
  const int wm = wave >> 2, wn = wave & 3;
  const int lr = lane & 15, g = lane >> 4;

  // staging source (inverse of the LDS permutation): thread chunk o=j*8192+tid*16
  // maps to logical row rsrc+j*128, elem col sce
  const int rsrc = ((tid >> 5) << 3) | ((tid & 7) ^ ((tid >> 3) & 3));
  const int sce = ((tid >> 3) & 3) << 3;
  // read-side: logical (row r, chunk g) -> byte (r&~7)*64 + g*128 + ((r&7)^g)*16
  const int rxor = g * 128 + (((lr & 7) ^ g) << 4);
  const int abase = (wm * 128) << 6;
  const int bbase = (wn * 64) << 6;

  f32x4 acc[8][4] = {};
  const int niter = K / 64;

#define STG_A(kt, sl, j)                                                      \
  gld16(A + (size_t)(row0 + (j) * 128 + rsrc) * K + (kt) * 32 + sce,          \
        (char*)&AS[sl][0] + (j) * 8192 + wave * 1024)
#define STG_B(kt, sl, j)                                                      \
  gld16(Bm + (size_t)(col0 + (j) * 128 + rsrc) * K + (kt) * 32 + sce,         \
        (char*)&BS[sl][0] + (j) * 8192 + wave * 1024)

  // prologue: K-tile 0 -> slot 0, K-tile 1 -> slot 1
  STG_A(0, 0, 0); STG_A(0, 0, 1); STG_B(0, 0, 0); STG_B(0, 0, 1);
  STG_A(1, 1, 0); STG_A(1, 1, 1); STG_B(1, 1, 0); STG_B(1, 1, 1);
  asm volatile("s_waitcnt vmcnt(4)" ::: "memory");  // K-tile 0 landed
  __builtin_amdgcn_s_barrier();

  for (int it = 0; it < niter; it++) {
    const bool stg = (it + 1) < niter;
    const int slA = (2 * it) & 3, slB = (2 * it + 1) & 3;
    const int ktS = 2 * it + 2;
    const int ss0 = ktS & 3, ss1 = (ktS + 1) & 3;
    const char* Ab = (const char*)&AS[slA][0];
    const char* Bb = (const char*)&BS[slA][0];
    short8 bf[4], af[4];

    // ---- phase 0: K-tile 2it, m-half 0 ----
#pragma unroll
    for (int n = 0; n < 4; n++)
      bf[n] = *(const short8*)(Bb + bbase + ((n * 16 + (lr & 8)) << 6) + rxor);
#pragma unroll
    for (int m = 0; m < 4; m++)
      af[m] = *(const short8*)(Ab + abase + ((m * 16 + (lr & 8)) << 6) + rxor);
    if (stg) { STG_A(ktS, ss0, 0); STG_A(ktS, ss0, 1); }
    __builtin_amdgcn_s_barrier();
    asm volatile("s_waitcnt lgkmcnt(0)" ::: "memory");
    __builtin_amdgcn_sched_barrier(0);
    __builtin_amdgcn_s_setprio(1);
#pragma unroll
    for (int m = 0; m < 4; m++)
#pragma unroll
      for (int n = 0; n < 4; n++)
        acc[m][n] = __builtin_amdgcn_mfma_f32_16x16x32_bf16(af[m], bf[n], acc[m][n], 0, 0, 0);
    __builtin_amdgcn_s_setprio(0);
    __builtin_amdgcn_s_barrier();

    // ---- phase 1: K-tile 2it, m-half 1 ----
#pragma unroll
    for (int m = 0; m < 4; m++)
      af[m] = *(const short8*)(Ab + abase + ((64 + m * 16 + (lr & 8)) << 6) + rxor);
    if (stg) { STG_B(ktS, ss0, 0); STG_B(ktS, ss0, 1); }
    __builtin_amdgcn_s_barrier();
    asm volatile("s_waitcnt lgkmcnt(0)" ::: "memory");
    __builtin_amdgcn_sched_barrier(0);
    __builtin_amdgcn_s_setprio(1);
#pragma unroll
    for (int m = 0; m < 4; m++)
#pragma unroll
      for (int n = 0; n < 4; n++)
        acc[4 + m][n] = __builtin_amdgcn_mfma_f32_16x16x32_bf16(af[m], bf[n], acc[4 + m][n], 0, 0, 0);
    __builtin_amdgcn_s_setprio(0);
    if (stg) asm volatile("s_waitcnt vmcnt(4)" ::: "memory");  // K-tile 2it+1 landed
    else     asm volatile("s_waitcnt vmcnt(0)" ::: "memory");
    __builtin_amdgcn_s_barrier();

    // ---- phase 2: K-tile 2it+1, m-half 0 ----
    Ab = (const char*)&AS[slB][0];
    Bb = (const char*)&BS[slB][0];
#pragma unroll
    for (int n = 0; n < 4; n++)
      bf[n] = *(const short8*)(Bb + bbase + ((n * 16 + (lr & 8)) << 6) + rxor);
#pragma unroll
    for (int m = 0; m < 4; m++)
      af[m] = *(const short8*)(Ab + abase + ((m * 16 + (lr & 8)) << 6) + rxor);
    if (stg) { STG_A(ktS + 1, ss1, 0); STG_A(ktS + 1, ss1, 1); }
    __builtin_amdgcn_s_barrier();
    asm volatile("s_waitcnt lgkmcnt(0)" ::: "memory");
    __builtin_amdgcn_sched_barrier(0);
    __builtin_amdgcn_s_setprio(1);
#pragma unroll
    for (int m = 0; m < 4; m++)
#pragma unroll
      for (int n = 0; n < 4; n++)
        acc[m][n] = __builtin_amdgcn_mfma_f32_16x16x32_bf16(af[m], bf[n], acc[m][n], 0, 0, 0);
    __builtin_amdgcn_s_setprio(0);
    __builtin_amdgcn_s_barrier();

    // ---- phase 3: K-tile 2it+1, m-half 1 ----
#pragma unroll
    for (int m = 0; m < 4; m++)
      af[m] = *(const short8*)(Ab + abase + ((64 + m * 16 + (lr & 8)) << 6) + rxor);
    if (stg) { STG_B(ktS + 1, ss1, 0); STG_B(ktS + 1, ss1, 1); }
    __builtin_amdgcn_s_barrier();
    asm volatile("s_waitcnt lgkmcnt(0)" ::: "memory");
    __builtin_amdgcn_sched_barrier(0);
    __builtin_amdgcn_s_setprio(1);
#pragma unroll
    for (int m = 0; m < 4; m++)
#pragma unroll
      for (int n = 0; n < 4; n++)
        acc[4 + m][n] = __builtin_amdgcn_mfma_f32_16x16x32_bf16(af[m], bf[n], acc[4 + m][n], 0, 0, 0);
    __builtin_amdgcn_s_setprio(0);
    if (stg) asm volatile("s_waitcnt vmcnt(4)" ::: "memory");  // next K-tile 2it+2 landed
    __builtin_amdgcn_s_barrier();
  }
#undef STG_A
#undef STG_B

  const int cr = g * 4, cc = lr;
#pragma unroll
  for (int m = 0; m < 8; m++) {
#pragma unroll
    for (int n = 0; n < 4; n++) {
#pragma unroll
      for (int r = 0; r < 4; r++) {
        size_t idx = (size_t)(row0 + wm * 128 + m * 16 + cr + r) * N +
                     (col0 + wn * 64 + n * 16 + cc);
        if constexpr (sizeof(OutT) == 2) C[idx] = (OutT)f2bf(acc[m][n][r]);
        else C[idx] = acc[m][n][r];
      }
    }
  }
}

// ---------------- RMS-norm (q,k heads) + RoPE + split/cast --------------------
__global__ __launch_bounds__(256) void postproc_kernel(
    const u16* __restrict__ Cqkv, const float* __restrict__ cosT,
    const float* __restrict__ sinT, const float* __restrict__ qw,
    const float* __restrict__ kw, u16* __restrict__ qO, u16* __restrict__ kO,
    u16* __restrict__ vO) {
  const int row = blockIdx.x;
  const int b = row / SS, s = row % SS;
  const int wave = threadIdx.x >> 6, lane = threadIdx.x & 63;
  const u16* base = Cqkv + (size_t)row * NQKV;
  const int d0 = lane * 2;
  const float ATT_SCALE = 0.08838834764831843f * 1.4426950408889634f;  // D^-0.5 * log2e
  for (int hd = wave; hd < NH + 2 * NKV; hd += 4) {
    const u16* hp = base + hd * DH;
    ushort2 raw = *(const ushort2*)(hp + d0);
    if (hd < NH + NKV) {
      float v0 = bf2f(raw.x), v1 = bf2f(raw.y);
      float ss = v0 * v0 + v1 * v1;
#pragma unroll
      for (int off = 32; off > 0; off >>= 1) ss += __shfl_xor(ss, off);
      float inv = rsqrtf(ss * (1.0f / DH) + RMS_EPS);
      const float* w = (hd < NH) ? qw : kw;
      float n0 = v0 * inv * w[d0], n1 = v1 * inv * w[d0 + 1];
      float r0 = __shfl_xor(n0, 32), r1 = __shfl_xor(n1, 32);
      float sgn = (lane < 32) ? -1.f : 1.f;
      float c0 = cosT[s * DH + d0], c1 = cosT[s * DH + d0 + 1];
      float s0 = sinT[s * DH + d0], s1 = sinT[s * DH + d0 + 1];
      float o0 = n0 * c0 + sgn * r0 * s0;
      float o1 = n1 * c1 + sgn * r1 * s1;
      ushort2 o;
      if (hd < NH) {
        o.x = f2bf(o0 * ATT_SCALE);
        o.y = f2bf(o1 * ATT_SCALE);
        *(ushort2*)(qO + ((size_t)((b * NH + hd) * SS + s)) * DH + d0) = o;
      } else {
        o.x = f2bf(o0);
        o.y = f2bf(o1);
        *(ushort2*)(kO + ((size_t)((b * NKV + hd - NH) * SS + s)) * DH + d0) = o;
      }
    } else {
      *(ushort2*)(vO + ((size_t)((b * NKV + hd - NH - NKV) * SS + s)) * DH + d0) = raw;
    }
  }
}

// ---------------- V transpose: [b,hkv][S][D] -> [b,hkv][D][S] ----------------
__global__ __launch_bounds__(256) void transpose_v_kernel(const u16* __restrict__ v,
                                                          u16* __restrict__ vt) {
  __shared__ u16 tile[64][68];
  const int bh = blockIdx.z;
  const int st = blockIdx.x * 64;
  const int dt = blockIdx.y * 64;
  const int tid = threadIdx.x;
  const u16* src = v + ((size_t)bh * SS + st) * DH + dt;
#pragma unroll
  for (int it = 0; it < 4; it++) {
    int r = (tid >> 4) + it * 16, c = (tid & 15) * 4;
    *(u16x4*)&tile[r][c] = *(const u16x4*)(src + (size_t)r * DH + c);
  }
  __syncthreads();
  u16* dst = vt + ((size_t)bh * DH + dt) * SS + st;
#pragma unroll
  for (int it = 0; it < 4; it++) {
    int r2 = (tid >> 4) + it * 16, c2 = (tid & 15) * 4;
    u16x4 o;
    o.x = tile[c2][r2]; o.y = tile[c2 + 1][r2];
    o.z = tile[c2 + 2][r2]; o.w = tile[c2 + 3][r2];
    *(u16x4*)(dst + (size_t)r2 * SS + c2) = o;
  }
}

// ---------------- causal GQA flash attention ---------------------------------
__global__ __launch_bounds__(256, 2) void attn_kernel(
    const u16* __restrict__ Q, const u16* __restrict__ Kb,
    const u16* __restrict__ Vt, u16* __restrict__ O) {
  __shared__ __align__(16) u16 Ks[64 * 128];
  __shared__ __align__(16) u16 Vs[128 * 64];
  __shared__ __align__(16) u16 Plds[4][16 * 64];
  const int pid = blockIdx.x, h = blockIdx.y, b = blockIdx.z;
  const int hkv = h >> 2;
  const int tid = threadIdx.x;
  const int wave = tid >> 6, lane = tid & 63;
  const int lr = lane & 15, g = lane >> 4;
  const u16* qbase = Q + ((size_t)(b * NH + h) * SS) * DH;
  const u16* kbase = Kb + ((size_t)(b * NKV + hkv) * SS) * DH;
  const u16* vbase = Vt + ((size_t)(b * NKV + hkv) * DH) * SS;

  const int krow = tid >> 4;
  const int kcol = (tid & 15) * 8;
  const int kswz = kcol ^ ((krow & 7) << 3);
  const int vrow = tid >> 3;
  const int vcol = (tid & 7) * 8;
  const int vswz = vcol ^ ((vrow & 7) << 3);
  const int kx = (lr & 7) << 3;
  const int psw = (lr & 7) << 4;
  char* pl = (char*)&Plds[wave][0];

  int4 kr0, kr1, kr2, kr3, vr0, vr1, vr2, vr3;
#define STAGE_LOAD(T)                                                         \
  {                                                                           \
    const int kv0_ = (T) * 64;                                                \
    kr0 = *(const int4*)(kbase + (size_t)(kv0_ + krow) * DH + kcol);          \
    kr1 = *(const int4*)(kbase + (size_t)(kv0_ + krow + 16) * DH + kcol);     \
    kr2 = *(const int4*)(kbase + (size_t)(kv0_ + krow + 32) * DH + kcol);     \
    kr3 = *(const int4*)(kbase + (size_t)(kv0_ + krow + 48) * DH + kcol);     \
    vr0 = *(const int4*)(vbase + (size_t)(vrow) * SS + kv0_ + vcol);          \
    vr1 = *(const int4*)(vbase + (size_t)(vrow + 32) * SS + kv0_ + vcol);     \
    vr2 = *(const int4*)(vbase + (size_t)(vrow + 64) * SS + kv0_ + vcol);     \
    vr3 = *(const int4*)(vbase + (size_t)(vrow + 96) * SS + kv0_ + vcol);     \
  }
#define STAGE_WRITE()                                                         \
  {                                                                           \
    *(int4*)&Ks[(krow) * DH + kswz] = kr0;                                    \
    *(int4*)&Ks[(krow + 16) * DH + kswz] = kr1;                               \
    *(int4*)&Ks[(krow + 32) * DH + kswz] = kr2;                               \
    *(int4*)&Ks[(krow + 48) * DH + kswz] = kr3;                               \
    *(int4*)&Vs[(vrow) * 64 + vswz] = vr0;                                    \
    *(int4*)&Vs[(vrow + 32) * 64 + vswz] = vr1;                               \
    *(int4*)&Vs[(vrow + 64) * 64 + vswz] = vr2;                               \
    *(int4*)&Vs[(vrow + 96) * 64 + vswz] = vr3;                               \
  }

#pragma unroll 1
  for (int half = 0; half < 2; half++) {
    const int qt = half ? (SS / 64 - 1 - pid) : pid;
    const int q0 = qt * 64 + wave * 16;
    const int nt = qt + 1;

    short8 qf[4];
#pragma unroll
    for (int c = 0; c < 4; c++)
      qf[c] = *(const short8*)(qbase + (size_t)(q0 + lr) * DH + c * 32 + g * 8);

    f32x4 o_acc[8] = {};
    float l_run = 0.f;

    STAGE_LOAD(0);
    STAGE_WRITE();
    __syncthreads();

    for (int t = 0; t < nt; t++) {
      const int kv0 = t * 64;
      if (t + 1 < nt) STAGE_LOAD(t + 1);

      f32x4 sf[4] = {};
      __builtin_amdgcn_s_setprio(1);
#pragma unroll
      for (int n = 0; n < 4; n++) {
#pragma unroll
        for (int c = 0; c < 4; c++) {
          short8 kf = *(const short8*)&Ks[(n * 16 + lr) * DH + ((c * 32 + g * 8) ^ kx)];
          sf[n] = __builtin_amdgcn_mfma_f32_16x16x32_bf16(kf, qf[c], sf[n], 0, 0, 0);
        }
      }
      __builtin_amdgcn_s_setprio(0);

      const int qabs = q0 + lr;
      float p[4][4];
      float rs = 0.f;
#pragma unroll
      for (int n = 0; n < 4; n++) {
#pragma unroll
        for (int r = 0; r < 4; r++) {
          const int kvabs = kv0 + n * 16 + g * 4 + r;
          float e = exp2f(sf[n][r] - 17.312340490667562f);
          e = (kvabs <= qabs) ? e : 0.f;
          p[n][r] = e;
          rs += e;
        }
      }
      rs += __shfl_xor(rs, 16);
      rs += __shfl_xor(rs, 32);
      l_run += rs;

#pragma unroll
      for (int n = 0; n < 4; n++) {
        uint2 wv;
        wv.x = (unsigned)f2bf(p[n][0]) | ((unsigned)f2bf(p[n][1]) << 16);
        wv.y = (unsigned)f2bf(p[n][2]) | ((unsigned)f2bf(p[n][3]) << 16);
        *(uint2*)(pl + lr * 128 + ((32 * n + 8 * g) ^ psw)) = wv;
      }

      __builtin_amdgcn_s_setprio(1);
#pragma unroll
      for (int c2 = 0; c2 < 2; c2++) {
        short8 pf = *(const short8*)(pl + lr * 128 + ((64 * c2 + 16 * g) ^ psw));
#pragma unroll
        for (int n2 = 0; n2 < 8; n2++) {
          short8 vf = *(const short8*)&Vs[(n2 * 16 + lr) * 64 + ((c2 * 32 + g * 8) ^ kx)];
          o_acc[n2] = __builtin_amdgcn_mfma_f32_16x16x32_bf16(pf, vf, o_acc[n2], 0, 0, 0);
        }
      }
      __builtin_amdgcn_s_setprio(0);

      __syncthreads();
      if (t + 1 < nt) STAGE_WRITE();
      __syncthreads();
    }

#pragma unroll
    for (int r = 0; r < 4; r++) {
      const float ls = __shfl(l_run, (g << 4) | (g * 4 + r));
      const float inv = 1.0f / ls;
      u16* orow = O + ((size_t)(b * SS + q0 + g * 4 + r)) * (NH * DH) + h * DH;
#pragma unroll
      for (int n2 = 0; n2 < 8; n2++) orow[n2 * 16 + lr] = f2bf(o_acc[n2][r] * inv);
    }
  }
#undef STAGE_LOAD
#undef STAGE_WRITE
}

// -----------------------------------------------------------------------------
extern "C" void kernel_launch(void* const* d_in, const int* in_sizes, int n_in,
                              void* d_out, int out_size, void* d_ws, size_t ws_size,
                              hipStream_t stream) {
  const float* x    = (const float*)d_in[0];
  const float* cosT = (const float*)d_in[1];
  const float* sinT = (const float*)d_in[2];
  // d_in[3] = mask (causal, reconstructed analytically)
  const float* wq = (const float*)d_in[4];
  const float* wk = (const float*)d_in[5];
  const float* wv = (const float*)d_in[6];
  const float* wo = (const float*)d_in[7];
  const float* qw = (const float*)d_in[8];
  const float* kw = (const float*)d_in[9];
  float* out = (float*)d_out;

  char* p = (char*)d_ws;
  u16* xb    = (u16*)p; p += (size_t)MROWS * HSZ * 2;
  u16* wqkvb = (u16*)p; p += (size_t)NQKV * HSZ * 2;
  u16* wob   = (u16*)p; p += (size_t)HSZ * HSZ * 2;
  u16* cqkv  = (u16*)p; p += (size_t)MROWS * NQKV * 2;
  u16* qb    = (u16*)p; p += (size_t)BB * NH * SS * DH * 2;
  u16* kb    = (u16*)p; p += (size_t)BB * NKV * SS * DH * 2;
  u16* vb    = (u16*)p; p += (size_t)BB * NKV * SS * DH * 2;
  u16* vtb   = (u16*)p; p += (size_t)BB * NKV * SS * DH * 2;
  u16* aob   = (u16*)p; p += (size_t)MROWS * HSZ * 2;

  const int ncvt4 = (N_X + N_WQ + 2 * N_WK + N_WO) / 4;
  cvt_all_kernel<<<dim3(ncvt4 / 256), dim3(256), 0, stream>>>(
      x, wq, wk, wv, wo, xb, wqkvb, wob);

  gemm256<u16><<<dim3((MROWS / 256) * (NQKV / 256)), dim3(512), 0, stream>>>(
      xb, wqkvb, cqkv, MROWS, NQKV, HSZ, NQKV / 256);
  postproc_kernel<<<dim3(MROWS), dim3(256), 0, stream>>>(cqkv, cosT, sinT, qw, kw, qb, kb, vb);
  transpose_v_kernel<<<dim3(SS / 64, DH / 64, BB * NKV), dim3(256), 0, stream>>>(vb, vtb);
  attn_kernel<<<dim3(SS / 128, NH, BB), dim3(256), 0, stream>>>(qb, kb, vtb, aob);
  gemm256<float><<<dim3((MROWS / 256) * (HSZ / 256)), dim3(512), 0, stream>>>(
      aob, wob, out, MROWS, HSZ, HSZ, HSZ / 256);
}

// Round 6
// 338.054 us; speedup vs baseline: 1.1713x; 1.0830x over previous
//
#include <hip/hip_runtime.h>
#include <hip/hip_bf16.h>
#include <stdint.h>

typedef unsigned short u16;
typedef __attribute__((ext_vector_type(8))) short short8;
typedef __attribute__((ext_vector_type(4))) float f32x4;
typedef __attribute__((ext_vector_type(4))) unsigned short u16x4;

constexpr int BB = 2, SS = 2048, HSZ = 2048, NH = 16, NKV = 4, DH = 128;
constexpr int MROWS = BB * SS;             // 4096
constexpr int NQKV = (NH + 2 * NKV) * DH;  // 3072
constexpr float RMS_EPS = 1e-6f;

__device__ __forceinline__ u16 f2bf(float f) {
  __hip_bfloat16 h = __float2bfloat16(f);
  return *reinterpret_cast<u16*>(&h);
}
__device__ __forceinline__ float bf2f(u16 u) {
  __hip_bfloat16 h;
  *reinterpret_cast<u16*>(&h) = u;
  return __bfloat162float(h);
}

__device__ __forceinline__ void gld16(const void* g, void* l) {
  __builtin_amdgcn_global_load_lds(
      (const __attribute__((address_space(1))) void*)g,
      (__attribute__((address_space(3))) void*)l, 16, 0, 0);
}

template <int N>
__device__ __forceinline__ void wait_vmcnt() {
  if constexpr (N == 0) asm volatile("s_waitcnt vmcnt(0)" ::: "memory");
  else if constexpr (N == 3) asm volatile("s_waitcnt vmcnt(3)" ::: "memory");
  else if constexpr (N == 4) asm volatile("s_waitcnt vmcnt(4)" ::: "memory");
}

// ---------------- fp32 -> bf16 conversion: all 5 tensors, one launch ---------
constexpr int N_X = MROWS * HSZ;      // 8388608
constexpr int N_WQ = NH * DH * HSZ;   // 4194304
constexpr int N_WK = NKV * DH * HSZ;  // 1048576
constexpr int N_WO = HSZ * HSZ;       // 4194304
__global__ void cvt_all_kernel(const float* __restrict__ x, const float* __restrict__ wq,
                               const float* __restrict__ wk, const float* __restrict__ wv,
                               const float* __restrict__ wo, u16* __restrict__ xb,
                               u16* __restrict__ wqkvb, u16* __restrict__ wob) {
  const int X4 = N_X / 4, Q4 = N_WQ / 4, K4 = N_WK / 4;
  int i = blockIdx.x * blockDim.x + threadIdx.x;
  const float* src;
  u16* dst;
  int off;
  if (i < X4) { src = x; dst = xb; off = i; }
  else if (i < X4 + Q4) { src = wq; dst = wqkvb; off = i - X4; }
  else if (i < X4 + Q4 + K4) { src = wk; dst = wqkvb + N_WQ; off = i - X4 - Q4; }
  else if (i < X4 + Q4 + 2 * K4) { src = wv; dst = wqkvb + N_WQ + N_WK; off = i - X4 - Q4 - K4; }
  else { src = wo; dst = wob; off = i - X4 - Q4 - 2 * K4; }
  float4 v = reinterpret_cast<const float4*>(src)[off];
  u16x4 o;
  o.x = f2bf(v.x); o.y = f2bf(v.y); o.z = f2bf(v.z); o.w = f2bf(v.w);
  reinterpret_cast<u16x4*>(dst)[off] = o;
}

// ---------------- GEMM 256xBN: C[M][N] = A[M][K] @ B[N][K]^T -----------------
// 512 threads, 8 waves (WM x WN). BK=32, ring-4 K-tile slots; stage targets
// slot^2 (disjoint from both slots read this iteration -> no clobber race).
// Per K-tile phase: {ds_read frags -> stage next+2 -> MFMA -> counted vmcnt ->
// s_barrier -> sched_barrier}. No explicit lgkmcnt: plain C++ ds reads let the
// compiler emit incremental lgkmcnt(N) so reads overlap MFMA. vmcnt BEFORE the
// barrier = all waves' parts of the needed tile landed. Never vmcnt(0) except
// the tail. LDS layout (conflict-free, verified 0 in r5): chunk g of row r at
// (r&~7)*64 + g*128 + ((r&7)^g)*16; global_load_lds dest linear, permutation
// applied to the global SOURCE row (rule 21).
template <int BN, int WM, typename OutT>
__global__ __launch_bounds__(512, 2) void gemm256(
    const u16* __restrict__ A, const u16* __restrict__ Bm, OutT* __restrict__ C,
    int M, int N, int K, int nbn) {
  constexpr int WN = 8 / WM;
  constexpr int MF = (256 / WM) / 16;   // A frags per wave
  constexpr int NFr = (BN / WN) / 16;   // B frags per wave
  constexpr int BL = BN / 128;          // B gld16 loads per K-tile
  constexpr int LPT = 2 + BL;           // loads per K-tile
  __shared__ __align__(16) u16 AS[4][256 * 32];
  __shared__ __align__(16) u16 BS[4][BN * 32];
  const int tid = threadIdx.x;
  const int wave = tid >> 6, lane = tid & 63;
  const int nwg = gridDim.x, bid = blockIdx.x;
  const int wg = (bid & 7) * (nwg >> 3) + (bid >> 3);  // XCD swizzle (nwg%8==0)
  const int bm = wg / nbn, bn = wg % nbn;
  const int row0 = bm * 256, col0 = bn * BN;
  const int wm = wave / WN, wn = wave % WN;
  const int lr = lane & 15, g = lane >> 4;

  // staging source permutation (inverse of LDS layout), dest linear tid*16
  const int rsrc = ((tid >> 5) << 3) | ((tid & 7) ^ ((tid >> 3) & 3));  // 0..127
  const int sce = ((tid >> 3) & 3) << 3;
  // read side: logical (row r, k-chunk g) -> byte (r&~7)*64 + g*128 + ((r&7)^g)*16
  const int rxor = g * 128 + (((lr & 7) ^ g) << 4);
  const int abase = (wm * (256 / WM)) << 6;
  const int bbase = (wn * (BN / WN)) << 6;

  const u16* Ar0 = A + (size_t)(row0 + rsrc) * K + sce;
  const u16* Ar1 = A + (size_t)(row0 + 128 + rsrc) * K + sce;
  const u16* Br0 = Bm + (size_t)(col0 + rsrc) * K + sce;
  const u16* Br1 = Bm + (size_t)(col0 + 128 + rsrc) * K + sce;  // used iff BL==2

  auto stage = [&](int kt, int sl) {
    char* Ab = (char*)&AS[sl][0] + wave * 1024;
    char* Bb = (char*)&BS[sl][0] + wave * 1024;
    gld16(Ar0 + kt * 32, Ab);
    gld16(Ar1 + kt * 32, Ab + 8192);
    gld16(Br0 + kt * 32, Bb);
    if constexpr (BL == 2) gld16(Br1 + kt * 32, Bb + 8192);
  };

  f32x4 acc[MF][NFr] = {};
  const int niter = K / 64;

  // prologue: K-tile 0 -> slot 0, K-tile 1 -> slot 1
  stage(0, 0);
  stage(1, 1);
  wait_vmcnt<LPT>();  // tile 0 landed (this wave); barrier completes the tile
  __builtin_amdgcn_s_barrier();
  __builtin_amdgcn_sched_barrier(0);

  for (int it = 0; it < niter; it++) {
    const bool stg = (it + 1) < niter;
#pragma unroll
    for (int ph = 0; ph < 2; ph++) {
      const int kt = 2 * it + ph;
      const char* Ab = (const char*)&AS[kt & 3][0];
      const char* Bb = (const char*)&BS[kt & 3][0];
      short8 af[MF], bf[NFr];
#pragma unroll
      for (int m = 0; m < MF; m++)
        af[m] = *(const short8*)(Ab + abase + ((m * 16 + (lr & 8)) << 6) + rxor);
#pragma unroll
      for (int n = 0; n < NFr; n++)
        bf[n] = *(const short8*)(Bb + bbase + ((n * 16 + (lr & 8)) << 6) + rxor);
      if (stg) stage(kt + 2, (kt + 2) & 3);
      __builtin_amdgcn_s_setprio(1);
#pragma unroll
      for (int m = 0; m < MF; m++)
#pragma unroll
        for (int n = 0; n < NFr; n++)
          acc[m][n] = __builtin_amdgcn_mfma_f32_16x16x32_bf16(af[m], bf[n], acc[m][n], 0, 0, 0);
      __builtin_amdgcn_s_setprio(0);
      if (stg) wait_vmcnt<LPT>();        // tile kt+1 (or kt+2) landed
      else if (ph == 0) wait_vmcnt<0>(); // tail: last tile fully landed
      __builtin_amdgcn_s_barrier();
      __builtin_amdgcn_sched_barrier(0);
    }
  }

  const int cr = g * 4, cc = lr;
#pragma unroll
  for (int m = 0; m < MF; m++) {
#pragma unroll
    for (int n = 0; n < NFr; n++) {
#pragma unroll
      for (int r = 0; r < 4; r++) {
        size_t idx = (size_t)(row0 + wm * (256 / WM) + m * 16 + cr + r) * N +
                     (col0 + wn * (BN / WN) + n * 16 + cc);
        if constexpr (sizeof(OutT) == 2) C[idx] = (OutT)f2bf(acc[m][n][r]);
        else C[idx] = acc[m][n][r];
      }
    }
  }
}

// ---------------- RMS-norm (q,k heads) + RoPE + split/cast --------------------
__global__ __launch_bounds__(256) void postproc_kernel(
    const u16* __restrict__ Cqkv, const float* __restrict__ cosT,
    const float* __restrict__ sinT, const float* __restrict__ qw,
    const float* __restrict__ kw, u16* __restrict__ qO, u16* __restrict__ kO,
    u16* __restrict__ vO) {
  const int row = blockIdx.x;
  const int b = row / SS, s = row % SS;
  const int wave = threadIdx.x >> 6, lane = threadIdx.x & 63;
  const u16* base = Cqkv + (size_t)row * NQKV;
  const int d0 = lane * 2;
  const float ATT_SCALE = 0.08838834764831843f * 1.4426950408889634f;  // D^-0.5 * log2e
  for (int hd = wave; hd < NH + 2 * NKV; hd += 4) {
    const u16* hp = base + hd * DH;
    ushort2 raw = *(const ushort2*)(hp + d0);
    if (hd < NH + NKV) {
      float v0 = bf2f(raw.x), v1 = bf2f(raw.y);
      float ss = v0 * v0 + v1 * v1;
#pragma unroll
      for (int off = 32; off > 0; off >>= 1) ss += __shfl_xor(ss, off);
      float inv = rsqrtf(ss * (1.0f / DH) + RMS_EPS);
      const float* w = (hd < NH) ? qw : kw;
      float n0 = v0 * inv * w[d0], n1 = v1 * inv * w[d0 + 1];
      float r0 = __shfl_xor(n0, 32), r1 = __shfl_xor(n1, 32);
      float sgn = (lane < 32) ? -1.f : 1.f;
      float c0 = cosT[s * DH + d0], c1 = cosT[s * DH + d0 + 1];
      float s0 = sinT[s * DH + d0], s1 = sinT[s * DH + d0 + 1];
      float o0 = n0 * c0 + sgn * r0 * s0;
      float o1 = n1 * c1 + sgn * r1 * s1;
      ushort2 o;
      if (hd < NH) {
        o.x = f2bf(o0 * ATT_SCALE);
        o.y = f2bf(o1 * ATT_SCALE);
        *(ushort2*)(qO + ((size_t)((b * NH + hd) * SS + s)) * DH + d0) = o;
      } else {
        o.x = f2bf(o0);
        o.y = f2bf(o1);
        *(ushort2*)(kO + ((size_t)((b * NKV + hd - NH) * SS + s)) * DH + d0) = o;
      }
    } else {
      *(ushort2*)(vO + ((size_t)((b * NKV + hd - NH - NKV) * SS + s)) * DH + d0) = raw;
    }
  }
}

// ---------------- V transpose: [b,hkv][S][D] -> [b,hkv][D][S] ----------------
__global__ __launch_bounds__(256) void transpose_v_kernel(const u16* __restrict__ v,
                                                          u16* __restrict__ vt) {
  __shared__ u16 tile[64][68];
  const int bh = blockIdx.z;
  const int st = blockIdx.x * 64;
  const int dt = blockIdx.y * 64;
  const int tid = threadIdx.x;
  const u16* src = v + ((size_t)bh * SS + st) * DH + dt;
#pragma unroll
  for (int it = 0; it < 4; it++) {
    int r = (tid >> 4) + it * 16, c = (tid & 15) * 4;
    *(u16x4*)&tile[r][c] = *(const u16x4*)(src + (size_t)r * DH + c);
  }
  __syncthreads();
  u16* dst = vt + ((size_t)bh * DH + dt) * SS + st;
#pragma unroll
  for (int it = 0; it < 4; it++) {
    int r2 = (tid >> 4) + it * 16, c2 = (tid & 15) * 4;
    u16x4 o;
    o.x = tile[c2][r2]; o.y = tile[c2 + 1][r2];
    o.z = tile[c2 + 2][r2]; o.w = tile[c2 + 3][r2];
    *(u16x4*)(dst + (size_t)r2 * SS + c2) = o;
  }
}

// ---------------- causal GQA flash attention ---------------------------------
// grid (S/128 pairs, H, B); 4 waves; wave owns 16 q-rows; KV tiles of 64.
// Block processes q-tiles {pid, 31-pid} -> uniform 33 tile-units.
// Swapped QK^T; static-max softmax (p = exp2(S' - 12*log2e), exact bound).
// Only tile t==qt is causally partial -> unmasked fast path for t<qt.
__global__ __launch_bounds__(256, 2) void attn_kernel(
    const u16* __restrict__ Q, const u16* __restrict__ Kb,
    const u16* __restrict__ Vt, u16* __restrict__ O) {
  __shared__ __align__(16) u16 Ks[64 * 128];
  __shared__ __align__(16) u16 Vs[128 * 64];
  __shared__ __align__(16) u16 Plds[4][16 * 64];
  const int pid = blockIdx.x, h = blockIdx.y, b = blockIdx.z;
  const int hkv = h >> 2;
  const int tid = threadIdx.x;
  const int wave = tid >> 6, lane = tid & 63;
  const int lr = lane & 15, g = lane >> 4;
  const u16* qbase = Q + ((size_t)(b * NH + h) * SS) * DH;
  const u16* kbase = Kb + ((size_t)(b * NKV + hkv) * SS) * DH;
  const u16* vbase = Vt + ((size_t)(b * NKV + hkv) * DH) * SS;

  const int krow = tid >> 4;
  const int kcol = (tid & 15) * 8;
  const int kswz = kcol ^ ((krow & 7) << 3);
  const int vrow = tid >> 3;
  const int vcol = (tid & 7) * 8;
  const int vswz = vcol ^ ((vrow & 7) << 3);
  const int kx = (lr & 7) << 3;
  const int psw = (lr & 7) << 4;
  char* pl = (char*)&Plds[wave][0];

  int4 kr0, kr1, kr2, kr3, vr0, vr1, vr2, vr3;
#define STAGE_LOAD(T)                                                         \
  {                                                                           \
    const int kv0_ = (T) * 64;                                                \
    kr0 = *(const int4*)(kbase + (size_t)(kv0_ + krow) * DH + kcol);          \
    kr1 = *(const int4*)(kbase + (size_t)(kv0_ + krow + 16) * DH + kcol);     \
    kr2 = *(const int4*)(kbase + (size_t)(kv0_ + krow + 32) * DH + kcol);     \
    kr3 = *(const int4*)(kbase + (size_t)(kv0_ + krow + 48) * DH + kcol);     \
    vr0 = *(const int4*)(vbase + (size_t)(vrow) * SS + kv0_ + vcol);          \
    vr1 = *(const int4*)(vbase + (size_t)(vrow + 32) * SS + kv0_ + vcol);     \
    vr2 = *(const int4*)(vbase + (size_t)(vrow + 64) * SS + kv0_ + vcol);     \
    vr3 = *(const int4*)(vbase + (size_t)(vrow + 96) * SS + kv0_ + vcol);     \
  }
#define STAGE_WRITE()                                                         \
  {                                                                           \
    *(int4*)&Ks[(krow) * DH + kswz] = kr0;                                    \
    *(int4*)&Ks[(krow + 16) * DH + kswz] = kr1;                               \
    *(int4*)&Ks[(krow + 32) * DH + kswz] = kr2;                               \
    *(int4*)&Ks[(krow + 48) * DH + kswz] = kr3;                               \
    *(int4*)&Vs[(vrow) * 64 + vswz] = vr0;                                    \
    *(int4*)&Vs[(vrow + 32) * 64 + vswz] = vr1;                               \
    *(int4*)&Vs[(vrow + 64) * 64 + vswz] = vr2;                               \
    *(int4*)&Vs[(vrow + 96) * 64 + vswz] = vr3;                               \
  }

#pragma unroll 1
  for (int half = 0; half < 2; half++) {
    const int qt = half ? (SS / 64 - 1 - pid) : pid;
    const int q0 = qt * 64 + wave * 16;
    const int nt = qt + 1;

    short8 qf[4];
#pragma unroll
    for (int c = 0; c < 4; c++)
      qf[c] = *(const short8*)(qbase + (size_t)(q0 + lr) * DH + c * 32 + g * 8);

    f32x4 o_acc[8] = {};
    float l_run = 0.f;

    STAGE_LOAD(0);
    STAGE_WRITE();
    __syncthreads();

    for (int t = 0; t < nt; t++) {
      if (t + 1 < nt) STAGE_LOAD(t + 1);  // T14: in flight under compute

      // ---- swapped QK^T: S^T[64 kv][16 q] ----
      f32x4 sf[4] = {};
      __builtin_amdgcn_s_setprio(1);
#pragma unroll
      for (int n = 0; n < 4; n++) {
#pragma unroll
        for (int c = 0; c < 4; c++) {
          short8 kf = *(const short8*)&Ks[(n * 16 + lr) * DH + ((c * 32 + g * 8) ^ kx)];
          sf[n] = __builtin_amdgcn_mfma_f32_16x16x32_bf16(kf, qf[c], sf[n], 0, 0, 0);
        }
      }
      __builtin_amdgcn_s_setprio(0);

      // ---- softmax, static max; mask only on the diagonal tile ----
      float p[4][4];
      float rs = 0.f;
      if (t + 1 < nt) {
#pragma unroll
        for (int n = 0; n < 4; n++)
#pragma unroll
          for (int r = 0; r < 4; r++) {
            float e = exp2f(sf[n][r] - 17.312340490667562f);  // 12*log2e
            p[n][r] = e;
            rs += e;
          }
      } else {
        const int qabs = q0 + lr;
        const int kvb = t * 64;
#pragma unroll
        for (int n = 0; n < 4; n++)
#pragma unroll
          for (int r = 0; r < 4; r++) {
            const int kvabs = kvb + n * 16 + g * 4 + r;
            float e = exp2f(sf[n][r] - 17.312340490667562f);
            e = (kvabs <= qabs) ? e : 0.f;
            p[n][r] = e;
            rs += e;
          }
      }
      rs += __shfl_xor(rs, 16);
      rs += __shfl_xor(rs, 32);
      l_run += rs;

      // ---- pack P -> bf16 into wave-private LDS ----
#pragma unroll
      for (int n = 0; n < 4; n++) {
        uint2 wv;
        wv.x = (unsigned)f2bf(p[n][0]) | ((unsigned)f2bf(p[n][1]) << 16);
        wv.y = (unsigned)f2bf(p[n][2]) | ((unsigned)f2bf(p[n][3]) << 16);
        *(uint2*)(pl + lr * 128 + ((32 * n + 8 * g) ^ psw)) = wv;
      }

      // ---- PV: O[16 q][128 d] += P[16][64] @ V[64][128] ----
      __builtin_amdgcn_s_setprio(1);
#pragma unroll
      for (int c2 = 0; c2 < 2; c2++) {
        short8 pf = *(const short8*)(pl + lr * 128 + ((64 * c2 + 16 * g) ^ psw));
#pragma unroll
        for (int n2 = 0; n2 < 8; n2++) {
          short8 vf = *(const short8*)&Vs[(n2 * 16 + lr) * 64 + ((c2 * 32 + g * 8) ^ kx)];
          o_acc[n2] = __builtin_amdgcn_mfma_f32_16x16x32_bf16(pf, vf, o_acc[n2], 0, 0, 0);
        }
      }
      __builtin_amdgcn_s_setprio(0);

      __syncthreads();
      if (t + 1 < nt) STAGE_WRITE();
      __syncthreads();
    }

#pragma unroll
    for (int r = 0; r < 4; r++) {
      const float ls = __shfl(l_run, (g << 4) | (g * 4 + r));
      const float inv = 1.0f / ls;
      u16* orow = O + ((size_t)(b * SS + q0 + g * 4 + r)) * (NH * DH) + h * DH;
#pragma unroll
      for (int n2 = 0; n2 < 8; n2++) orow[n2 * 16 + lr] = f2bf(o_acc[n2][r] * inv);
    }
  }
#undef STAGE_LOAD
#undef STAGE_WRITE
}

// -----------------------------------------------------------------------------
extern "C" void kernel_launch(void* const* d_in, const int* in_sizes, int n_in,
                              void* d_out, int out_size, void* d_ws, size_t ws_size,
                              hipStream_t stream) {
  const float* x    = (const float*)d_in[0];
  const float* cosT = (const float*)d_in[1];
  const float* sinT = (const float*)d_in[2];
  // d_in[3] = mask (causal, reconstructed analytically)
  const float* wq = (const float*)d_in[4];
  const float* wk = (const float*)d_in[5];
  const float* wv = (const float*)d_in[6];
  const float* wo = (const float*)d_in[7];
  const float* qw = (const float*)d_in[8];
  const float* kw = (const float*)d_in[9];
  float* out = (float*)d_out;

  char* p = (char*)d_ws;
  u16* xb    = (u16*)p; p += (size_t)MROWS * HSZ * 2;
  u16* wqkvb = (u16*)p; p += (size_t)NQKV * HSZ * 2;
  u16* wob   = (u16*)p; p += (size_t)HSZ * HSZ * 2;
  u16* cqkv  = (u16*)p; p += (size_t)MROWS * NQKV * 2;
  u16* qb    = (u16*)p; p += (size_t)BB * NH * SS * DH * 2;
  u16* kb    = (u16*)p; p += (size_t)BB * NKV * SS * DH * 2;
  u16* vb    = (u16*)p; p += (size_t)BB * NKV * SS * DH * 2;
  u16* vtb   = (u16*)p; p += (size_t)BB * NKV * SS * DH * 2;
  u16* aob   = (u16*)p; p += (size_t)MROWS * HSZ * 2;

  const int ncvt4 = (N_X + N_WQ + 2 * N_WK + N_WO) / 4;
  cvt_all_kernel<<<dim3(ncvt4 / 256), dim3(256), 0, stream>>>(
      x, wq, wk, wv, wo, xb, wqkvb, wob);

  gemm256<256, 2, u16><<<dim3((MROWS / 256) * (NQKV / 256)), dim3(512), 0, stream>>>(
      xb, wqkvb, cqkv, MROWS, NQKV, HSZ, NQKV / 256);
  postproc_kernel<<<dim3(MROWS), dim3(256), 0, stream>>>(cqkv, cosT, sinT, qw, kw, qb, kb, vb);
  transpose_v_kernel<<<dim3(SS / 64, DH / 64, BB * NKV), dim3(256), 0, stream>>>(vb, vtb);
  attn_kernel<<<dim3(SS / 128, NH, BB), dim3(256), 0, stream>>>(qb, kb, vtb, aob);
  gemm256<128, 4, float><<<dim3((MROWS / 256) * (HSZ / 128)), dim3(512), 0, stream>>>(
      aob, wob, out, MROWS, HSZ, HSZ, HSZ / 128);
}